// Round 24
// baseline (56.887 us; speedup 1.0000x reference)
//
#include <hip/hip_runtime.h>
#include <hip/hip_bf16.h>

// Problem constants: B=16, T=2048, D=512, HD=64, causal single-head attention.
#define NB   16
#define NT   2048
#define ND   512
#define NHD  64
// (1/sqrt(64)) * log2(e): folded into q so attention softmax uses exp2 directly.
#define QSCALE 0.1803368801111204f

typedef __attribute__((ext_vector_type(8)))  short bf16x8;   // 8 bf16 / 4 VGPR
typedef __attribute__((ext_vector_type(4)))  short bf16x4;   // 8-byte pack
typedef __attribute__((ext_vector_type(4)))  float f32x4;
typedef __attribute__((ext_vector_type(16))) float f32x16;   // 32x32 MFMA acc

static __device__ __forceinline__ short f2bf(float f) {
    union { __hip_bfloat16 h; short s; } u;
    u.h = __float2bfloat16(f);
    return u.s;
}
static __device__ __forceinline__ float bf2f(short s) {
    union { unsigned u; float f; } x;
    x.u = ((unsigned)(unsigned short)s) << 16;
    return x.f;
}
// Raw v_exp_f32 (2^x); HW handles our domain (scores ~N(0,1.44), -1e30 -> 0).
static __device__ __forceinline__ float fexp2(float x) {
    float r; asm("v_exp_f32 %0, %1" : "=v"(r) : "v"(x)); return r;
}
// Packed f32x2 -> bf16x2 in ONE instruction. dst = {lo: bf16(a), hi: bf16(b)}.
static __device__ __forceinline__ unsigned cvtpk(float a, float b) {
    unsigned r;
    asm("v_cvt_pk_bf16_f32 %0, %1, %2" : "=v"(r) : "v"(a), "v"(b));
    return r;
}
// async global->LDS 16B: per-lane global src, wave-uniform-base+lane*16 LDS dst.
static __device__ __forceinline__ void gll16(const void* g, void* l) {
    __builtin_amdgcn_global_load_lds(
        (const __attribute__((address_space(1))) unsigned int*)g,
        (__attribute__((address_space(3))) unsigned int*)l, 16, 0, 0);
}
// v_permlane32_swap_b32 vdst(a), vsrc(b): a.lanes[32:63] <-> b.lanes[0:31].
static __device__ __forceinline__ void plswap(unsigned a, unsigned b,
                                              unsigned& x, unsigned& y) {
#if __has_builtin(__builtin_amdgcn_permlane32_swap)
    auto rr = __builtin_amdgcn_permlane32_swap(a, b, false, false);
    x = rr[0]; y = rr[1];
#else
    int hi = (threadIdx.x & 63) >> 5;
    unsigned pb_ = __shfl_xor(b, 32), pa_ = __shfl_xor(a, 32);
    x = hi ? pb_ : a;
    y = hi ? b : pa_;
#endif
}

// Counted-vmcnt wait (T4): never drain to 0 in the steady-state loop.
#define VWAIT(N) do { asm volatile("s_waitcnt vmcnt(" #N ")" ::: "memory"); \
                      __builtin_amdgcn_sched_barrier(0); } while (0)
// Raw barrier WITHOUT the implicit vmcnt(0) drain of __syncthreads.
#define BAR() do { __builtin_amdgcn_s_barrier(); \
                   __builtin_amdgcn_sched_barrier(0); } while (0)
#define LGKM0_BAR() do { asm volatile("s_waitcnt lgkmcnt(0)" ::: "memory"); \
                         __builtin_amdgcn_sched_barrier(0); \
                         __builtin_amdgcn_s_barrier(); \
                         __builtin_amdgcn_sched_barrier(0); } while (0)

// blocks assigned to q-tile qt (proportional KV-split, chunk <= 7 tiles)
#define NBQ(qt) ((2 * (qt) + 8) / 7)
#define SWZ(r) ((((r) & 7) + ((r) >> 3)) & 7)

// ---------------------------------------------------------------------------
// Kernel 1: transpose W (f32 [512][64]) -> Wt (bf16 [3][64][512])
// ---------------------------------------------------------------------------
__global__ __launch_bounds__(256) void wtrans_kernel(
    const float* __restrict__ Wq, const float* __restrict__ Wk,
    const float* __restrict__ Wv, short* __restrict__ wt) {
    int tid = blockIdx.x * 256 + threadIdx.x;       // 0 .. 3*64*512-1
    int k = tid & (ND - 1);
    int c = (tid >> 9) & (NHD - 1);
    int m = tid >> 15;                              // 0..2
    const float* W = (m == 0) ? Wq : (m == 1) ? Wk : Wv;
    wt[tid] = f2bf(W[k * NHD + c]);                 // wt[(m*64+c)*512+k]
}

// ---------------------------------------------------------------------------
// Kernel 2: QKV projection GEMM (r17 winner) + r24: NON-TEMPORAL x loads.
// x is a 64MB single-pass cold stream; every prior lever (issue depth r18,
// registers r16, barrier domains r22, chunk size r23) was null at 2.6 TB/s.
// The untested subsystem is cache ALLOCATION on the read path: nt bypasses
// L1/L2 line allocation (x has zero reuse; poison fills evict it anyway).
// W loads stay cached (reused by all 512 blocks).
// ---------------------------------------------------------------------------
__global__ __launch_bounds__(256, 4) void qkv_gemm_kernel(
    const float* __restrict__ x, const short* __restrict__ wt,
    short* __restrict__ qws, short* __restrict__ kws, short* __restrict__ vtws) {
    int t    = threadIdx.x;
    int lane = t & 63;
    int q16  = lane & 15;
    int g    = lane >> 4;
    int wv   = t >> 6;
    int wm   = wv >> 1, wn = wv & 1;
    long R0  = (long)blockIdx.x * 64;

    __shared__ __align__(16) short Xt[64 * 64];     // [token][k] 8KB swizzled
    __shared__ __align__(16) short Wl[192 * 64];    // [col][k]  24KB swizzled

    int xrow = t >> 4, xquad = t & 15;              // X: 4 rounds of 16 rows
    int wrow = t >> 3, wseg = t & 7;                // W: 6 rounds of 32 rows

    const float* xg = x + (R0 + xrow) * ND + xquad * 4;
    const short* wg = wt + wrow * ND + wseg * 8;

    f32x4 xr[4];
    bf16x8 wr[6];
    auto LOAD = [&](int ch) {
#pragma unroll
        for (int i = 0; i < 4; ++i)
            xr[i] = __builtin_nontemporal_load(
                        (const f32x4*)(xg + (long)i * 16 * ND + ch * 64));
#pragma unroll
        for (int i = 0; i < 6; ++i)
            wr[i] = *(const bf16x8*)(wg + (long)i * 32 * ND + ch * 64);
    };
    auto STORE_LDS = [&]() {
#pragma unroll
        for (int i = 0; i < 4; ++i) {
            bf16x4 c;
#pragma unroll
            for (int j = 0; j < 4; ++j) c[j] = f2bf(xr[i][j]);
            int row = i * 16 + xrow;
            *(bf16x4*)((char*)Xt + row * 128 +
                       (((xquad >> 1) * 16) ^ (SWZ(row) << 4)) + (xquad & 1) * 8) = c;
        }
#pragma unroll
        for (int i = 0; i < 6; ++i) {
            int row = i * 32 + wrow;
            *(bf16x8*)((char*)Wl + row * 128 + ((wseg * 16) ^ (SWZ(row) << 4))) = wr[i];
        }
    };

    f32x4 acc[2][6];
#pragma unroll
    for (int mi = 0; mi < 2; ++mi)
#pragma unroll
        for (int ni = 0; ni < 6; ++ni) acc[mi][ni] = (f32x4){0.f, 0.f, 0.f, 0.f};

    LOAD(0);
    for (int ch = 0; ch < 8; ++ch) {
        STORE_LDS();                    // waits ONLY the regs it consumes
        if (ch + 1 < 8) LOAD(ch + 1);   // stays in flight across barriers
        LGKM0_BAR();                    // ds_writes visible; NO vmcnt drain
        __builtin_amdgcn_s_setprio(1);
#pragma unroll
        for (int kk = 0; kk < 2; ++kk) {
            bf16x8 a[2];
#pragma unroll
            for (int mi = 0; mi < 2; ++mi) {
                int row = wm * 32 + mi * 16 + q16;
                a[mi] = *(const bf16x8*)((char*)Xt + row * 128 +
                         ((kk * 64 + g * 16) ^ (SWZ(row) << 4)));
            }
#pragma unroll
            for (int ni = 0; ni < 6; ++ni) {
                int row = wn * 96 + ni * 16 + q16;
                bf16x8 b = *(const bf16x8*)((char*)Wl + row * 128 +
                            ((kk * 64 + g * 16) ^ (SWZ(row) << 4)));
                acc[0][ni] = __builtin_amdgcn_mfma_f32_16x16x32_bf16(a[0], b, acc[0][ni], 0, 0, 0);
                acc[1][ni] = __builtin_amdgcn_mfma_f32_16x16x32_bf16(a[1], b, acc[1][ni], 0, 0, 0);
            }
        }
        __builtin_amdgcn_s_setprio(0);
        BAR();                          // reads done; next STORE_LDS may write
    }

    int b = (int)(R0 >> 11);
#pragma unroll
    for (int mi = 0; mi < 2; ++mi) {
        long tok0 = R0 + wm * 32 + mi * 16 + g * 4;
#pragma unroll
        for (int ni = 0; ni < 6; ++ni) {
            int col = wn * 96 + ni * 16 + q16;
            int m = col >> 6, c64 = col & 63;       // uniform per (wn,ni)
            if (m == 0) {
#pragma unroll
                for (int r = 0; r < 4; ++r)
                    qws[(tok0 + r) * NHD + c64] = f2bf(acc[mi][ni][r] * QSCALE);
            } else if (m == 1) {
#pragma unroll
                for (int r = 0; r < 4; ++r)
                    kws[(tok0 + r) * NHD + c64] = f2bf(acc[mi][ni][r]);
            } else {
                bf16x4 vp;
#pragma unroll
                for (int r = 0; r < 4; ++r) vp[r] = f2bf(acc[mi][ni][r]);
                *(bf16x4*)(vtws + (long)(b * NHD + c64) * NT +
                           (int)(tok0 & 2047)) = vp;
            }
        }
    }
}

// ---------------------------------------------------------------------------
// Kernel 3: causal flash attention partial (r20, unchanged).
// ---------------------------------------------------------------------------
__global__ __launch_bounds__(256, 3) void attn_kernel(
    const short* __restrict__ qws, const short* __restrict__ kws,
    const short* __restrict__ vtws, short* __restrict__ Opart,
    float* __restrict__ lpart, float* __restrict__ out) {
    int bid  = blockIdx.x;
    int xcd  = bid & 7;
    int j    = bid >> 3;                // 0..91 within XCD
    int b    = xcd * 2 + (j >= 46);     // batch: 2 per XCD
    int j2   = (j >= 46) ? j - 46 : j;  // 0..45
    int qt = 0, chk = 0;
    {
        int acc = 0;
        for (int q = 15; q >= 0; --q) {
            int nbq = NBQ(q);
            if (j2 < acc + nbq) { qt = q; chk = j2 - acc; break; }
            acc += nbq;
        }
    }
    int n    = 2 * qt + 2;              // kv tiles covering this q-tile
    int nbq  = NBQ(qt);
    int tlo  = (chk * n) / nbq;
    int thi  = ((chk + 1) * n) / nbq;

    int tid  = threadIdx.x;
    int lane = tid & 63;
    int wv   = tid >> 6;                // 0..3
    int l31  = lane & 31;               // q column within wave tile
    int hi   = lane >> 5;

    __shared__ __align__(16) short Kt[3][64 * 64];  // [key][hd]  3x8KB swizzled
    __shared__ __align__(16) short Vt[3][64 * 64];  // [hd][key]  3x8KB swizzled

    int qr0w = qt * 128 + wv * 32;      // wave's first q row
    int qrow = qr0w + l31;

    const short* qb = qws + (long)(b * NT + qrow) * NHD;
    bf16x8 qf0 = *(const bf16x8*)(qb + hi * 8);
    bf16x8 qf1 = *(const bf16x8*)(qb + 16 + hi * 8);
    bf16x8 qf2 = *(const bf16x8*)(qb + 32 + hi * 8);
    bf16x8 qf3 = *(const bf16x8*)(qb + 48 + hi * 8);
    asm volatile("s_waitcnt vmcnt(0)" ::: "memory");
    asm volatile("" : "+v"(qf0), "+v"(qf1), "+v"(qf2), "+v"(qf3));
    __builtin_amdgcn_sched_barrier(0);

    int srow = tid >> 3, ssw = tid & 7;
    int sA_ = ssw ^ SWZ(srow);
    int sB_ = ssw ^ (((srow & 7) + (srow >> 3) + 4) & 7);      // rows +32
    const char* kT = (const char*)(kws  + (long)b * NT * NHD);
    const char* vT = (const char*)(vtws + (long)b * NHD * NT);
    auto STAGE = [&](int kv0, int buf) {            // 4 gll16 per thread
        char* lk = (char*)Kt + buf * 8192 + tid * 16;
        char* lv = (char*)Vt + buf * 8192 + tid * 16;
        gll16(kT + (long)(kv0 + srow) * 128 + sA_ * 16, lk);
        gll16(kT + (long)(kv0 + srow + 32) * 128 + sB_ * 16, lk + 4096);
        gll16(vT + (long)srow * 4096 + kv0 * 2 + sA_ * 16, lv);
        gll16(vT + (long)(srow + 32) * 4096 + kv0 * 2 + sB_ * 16, lv + 4096);
    };

    int swzq = SWZ(l31);
    int sw1  = swzq << 4;               // read-XOR for rows 0..31 (row = l31)
    int sw2  = ((swzq + 4) & 7) << 4;   // read-XOR for rows 32..63

    bf16x8 ones;
#pragma unroll
    for (int i = 0; i < 8; ++i) ones[i] = (short)0x3F80;   // bf16 1.0

    f32x16 oL, oH, lacc;
#pragma unroll
    for (int i = 0; i < 16; ++i) { oL[i] = 0.f; oH[i] = 0.f; lacc[i] = 0.f; }

    auto COMPUTE = [&](int kvi, int buf) {
        const char* kcur = (const char*)Kt + buf * 8192;
        const char* vcur = (const char*)Vt + buf * 8192;
        int k0 = kvi * 64;
        if (k0 > qr0w + 31) return;     // fully masked for this wave

        f32x16 sA, sB;
#pragma unroll
        for (int i = 0; i < 16; ++i) { sA[i] = 0.f; sB[i] = 0.f; }
        __builtin_amdgcn_s_setprio(1);
#pragma unroll
        for (int c = 0; c < 4; ++c) {
            bf16x8 qf = (c == 0) ? qf0 : (c == 1) ? qf1 : (c == 2) ? qf2 : qf3;
            bf16x8 kfA = *(const bf16x8*)(kcur + l31 * 128 +
                          ((c * 32 + hi * 16) ^ sw1));
            bf16x8 kfB = *(const bf16x8*)(kcur + (32 + l31) * 128 +
                          ((c * 32 + hi * 16) ^ sw2));
            sA = __builtin_amdgcn_mfma_f32_32x32x16_bf16(kfA, qf, sA, 0, 0, 0);
            sB = __builtin_amdgcn_mfma_f32_32x32x16_bf16(kfB, qf, sB, 0, 0, 0);
        }
        __builtin_amdgcn_s_setprio(0);

        bool msk = (k0 + 63 > qr0w);
        unsigned WA[8], WB[8];
#pragma unroll
        for (int m = 0; m < 4; ++m) {
#pragma unroll
            for (int t2 = 0; t2 < 4; ++t2) {
                int kloc = m * 8 + 4 * hi + t2;     // key within 32-block
                float va = sA[m * 4 + t2];
                float vb = sB[m * 4 + t2];
                if (msk) {
                    if (k0 + kloc > qrow)      va = -1e30f;
                    if (k0 + 32 + kloc > qrow) vb = -1e30f;
                }
                sA[m * 4 + t2] = fexp2(va);         // raw v_exp_f32
                sB[m * 4 + t2] = fexp2(vb);
            }
        }
#pragma unroll
        for (int p2 = 0; p2 < 8; ++p2) {            // raw v_cvt_pk_bf16_f32
            WA[p2] = cvtpk(sA[p2 * 2], sA[p2 * 2 + 1]);
            WB[p2] = cvtpk(sB[p2 * 2], sB[p2 * 2 + 1]);
        }

        bf16x8 pf0, pf1, pf2, pf3;
        {
            union { unsigned u[4]; bf16x8 v; } f;
            unsigned x, y;
            plswap(WA[0], WA[2], x, y); f.u[0] = x; f.u[2] = y;
            plswap(WA[1], WA[3], x, y); f.u[1] = x; f.u[3] = y;
            pf0 = f.v;
            plswap(WA[4], WA[6], x, y); f.u[0] = x; f.u[2] = y;
            plswap(WA[5], WA[7], x, y); f.u[1] = x; f.u[3] = y;
            pf1 = f.v;
            plswap(WB[0], WB[2], x, y); f.u[0] = x; f.u[2] = y;
            plswap(WB[1], WB[3], x, y); f.u[1] = x; f.u[3] = y;
            pf2 = f.v;
            plswap(WB[4], WB[6], x, y); f.u[0] = x; f.u[2] = y;
            plswap(WB[5], WB[7], x, y); f.u[1] = x; f.u[3] = y;
            pf3 = f.v;
        }

        __builtin_amdgcn_s_setprio(1);
#pragma unroll
        for (int kc = 0; kc < 4; ++kc) {
            bf16x8 pf = (kc == 0) ? pf0 : (kc == 1) ? pf1 : (kc == 2) ? pf2 : pf3;
            bf16x8 vfL = *(const bf16x8*)(vcur + l31 * 128 +
                          ((kc * 32 + hi * 16) ^ sw1));
            bf16x8 vfH = *(const bf16x8*)(vcur + (32 + l31) * 128 +
                          ((kc * 32 + hi * 16) ^ sw2));
            oL = __builtin_amdgcn_mfma_f32_32x32x16_bf16(vfL, pf, oL, 0, 0, 0);
            oH = __builtin_amdgcn_mfma_f32_32x32x16_bf16(vfH, pf, oH, 0, 0, 0);
            lacc = __builtin_amdgcn_mfma_f32_32x32x16_bf16(ones, pf, lacc, 0, 0, 0);
        }
        __builtin_amdgcn_s_setprio(0);
    };

    {
        int nt = thi - tlo;
        STAGE(tlo * 64, 0);
        if (nt > 1) STAGE((tlo + 1) * 64, 1);
        if (nt > 2) STAGE((tlo + 2) * 64, 2);

        int i = tlo, bc = 0;
        for (; i + 3 < thi; ++i) {
            VWAIT(8);
            BAR();
            COMPUTE(i, bc);
            BAR();
            STAGE((i + 3) * 64, bc);
            bc = (bc == 2) ? 0 : bc + 1;
        }
        if (thi - i == 3) {
            VWAIT(8); BAR(); COMPUTE(i, bc); BAR();
            bc = (bc == 2) ? 0 : bc + 1; ++i;
        }
        if (thi - i == 2) {
            VWAIT(4); BAR(); COMPUTE(i, bc); BAR();
            bc = (bc == 2) ? 0 : bc + 1; ++i;
        }
        if (thi - i == 1) {
            VWAIT(0); BAR(); COMPUTE(i, bc);
        }
    }

    if (nbq == 1) {
        // sole owner of these rows: normalized DIRECT output, no partials.
        float inv = 1.0f / lacc[0];
        float* od = out + ((long)(b << 11) + qt * 128 + wv * 32 + l31) * 64;
#pragma unroll
        for (int m = 0; m < 4; ++m) {
            f32x4 vL, vH;
#pragma unroll
            for (int t2 = 0; t2 < 4; ++t2) {
                vL[t2] = oL[m * 4 + t2] * inv;
                vH[t2] = oH[m * 4 + t2] * inv;
            }
            *(f32x4*)(od + m * 8 + 4 * hi)      = vL;
            *(f32x4*)(od + 32 + m * 8 + 4 * hi) = vH;
        }
        return;
    }

    // ---- epilogue: l = lacc[0] (all rows/cols of ones-MFMA equal) ----
    long prow = (long)chk * 32768 + (b << 11) + qt * 128 + wv * 32 + l31;
    short* od = Opart + prow * 64;
#pragma unroll
    for (int m = 0; m < 4; ++m) {
        bf16x4 a, c;
#pragma unroll
        for (int t2 = 0; t2 < 4; ++t2) { a[t2] = f2bf(oL[m * 4 + t2]); c[t2] = f2bf(oH[m * 4 + t2]); }
        *(bf16x4*)(od + m * 8 + 4 * hi)      = a;   // hd = m*8 + 4hi + t2
        *(bf16x4*)(od + 32 + m * 8 + 4 * hi) = c;   // hd block 32..63
    }
    if (hi == 0) lpart[prow] = lacc[0];
}

// ---------------------------------------------------------------------------
// Kernel 4: merge the per-(b,qt) chunk partials (qt>=3 only).
// ---------------------------------------------------------------------------
__global__ __launch_bounds__(256) void merge_kernel(
    const short* __restrict__ Opart, const float* __restrict__ lpart,
    float* __restrict__ out) {
    int idx  = blockIdx.x * 256 + threadIdx.x;      // 0 .. 262143
    int ridx = idx >> 3;                            // output row (== partial row)
    int h8   = idx & 7;                             // 8-hd chunk
    int qt   = (ridx >> 7) & 15;
    int nbq  = NBQ(qt);
    if (nbq == 1) return;                           // written directly by attn
    float lsum = 0.f;
    f32x4 r0 = (f32x4){0.f, 0.f, 0.f, 0.f};
    f32x4 r1 = (f32x4){0.f, 0.f, 0.f, 0.f};
    for (int s = 0; s < nbq; ++s) {
        lsum += lpart[s * 32768 + ridx];
        bf16x8 a = *(const bf16x8*)(Opart + (long)s * 2097152 + (long)ridx * 64 + h8 * 8);
#pragma unroll
        for (int jj = 0; jj < 4; ++jj) {
            r0[jj] += bf2f(a[jj]);
            r1[jj] += bf2f(a[4 + jj]);
        }
    }
    float inv = 1.0f / lsum;
    r0 *= inv; r1 *= inv;
    float* dst = out + (long)ridx * 64 + h8 * 8;
    *(f32x4*)dst = r0;
    *(f32x4*)(dst + 4) = r1;
}

// ---------------------------------------------------------------------------
extern "C" void kernel_launch(void* const* d_in, const int* in_sizes, int n_in,
                              void* d_out, int out_size, void* d_ws, size_t ws_size,
                              hipStream_t stream) {
    const float* x  = (const float*)d_in[0];
    const float* Wq = (const float*)d_in[1];
    const float* Wk = (const float*)d_in[2];
    const float* Wv = (const float*)d_in[3];
    float* out = (float*)d_out;

    float* fb    = (float*)d_ws;
    float* lpart = fb;                              // 5*32768 f32 (640KB)
    short* Opart = (short*)(fb + 5 * 32768);        // 5*32768*64 bf16 (20MB)
    short* qws   = Opart + (long)5 * 2097152;       // [32768][64] bf16 (pre-scaled)
    short* kws   = qws + (long)2097152;             // [32768][64] bf16
    short* vtws  = kws + (long)2097152;             // [16][64][2048] bf16
    short* wt    = vtws + (long)2097152;            // [3][64][512] bf16

    wtrans_kernel<<<384, 256, 0, stream>>>(Wq, Wk, Wv, wt);
    qkv_gemm_kernel<<<512, 256, 0, stream>>>(x, wt, qws, kws, vtws);
    attn_kernel<<<736, 256, 0, stream>>>(qws, kws, vtws, Opart, lpart, out);
    merge_kernel<<<1024, 256, 0, stream>>>(Opart, lpart, out);
}

// Round 25
// 49.702 us; speedup vs baseline: 1.1446x; 1.1446x over previous
//
#include <hip/hip_runtime.h>
#include <hip/hip_bf16.h>

// Problem constants: B=16, T=2048, D=512, HD=64, causal single-head attention.
#define NB   16
#define NT   2048
#define ND   512
#define NHD  64
// (1/sqrt(64)) * log2(e): folded into q so attention softmax uses exp2 directly.
#define QSCALE 0.1803368801111204f

typedef __attribute__((ext_vector_type(8)))  short bf16x8;   // 8 bf16 / 4 VGPR
typedef __attribute__((ext_vector_type(4)))  short bf16x4;   // 8-byte pack
typedef __attribute__((ext_vector_type(4)))  float f32x4;
typedef __attribute__((ext_vector_type(16))) float f32x16;   // 32x32 MFMA acc

static __device__ __forceinline__ short f2bf(float f) {
    union { __hip_bfloat16 h; short s; } u;
    u.h = __float2bfloat16(f);
    return u.s;
}
static __device__ __forceinline__ float bf2f(short s) {
    union { unsigned u; float f; } x;
    x.u = ((unsigned)(unsigned short)s) << 16;
    return x.f;
}
// Raw v_exp_f32 (2^x); HW handles our domain (scores ~N(0,1.44), -1e30 -> 0).
static __device__ __forceinline__ float fexp2(float x) {
    float r; asm("v_exp_f32 %0, %1" : "=v"(r) : "v"(x)); return r;
}
// Packed f32x2 -> bf16x2 in ONE instruction. dst = {lo: bf16(a), hi: bf16(b)}.
static __device__ __forceinline__ unsigned cvtpk(float a, float b) {
    unsigned r;
    asm("v_cvt_pk_bf16_f32 %0, %1, %2" : "=v"(r) : "v"(a), "v"(b));
    return r;
}
// async global->LDS 16B: per-lane global src, wave-uniform-base+lane*16 LDS dst.
static __device__ __forceinline__ void gll16(const void* g, void* l) {
    __builtin_amdgcn_global_load_lds(
        (const __attribute__((address_space(1))) unsigned int*)g,
        (__attribute__((address_space(3))) unsigned int*)l, 16, 0, 0);
}
// v_permlane32_swap_b32 vdst(a), vsrc(b): a.lanes[32:63] <-> b.lanes[0:31].
static __device__ __forceinline__ void plswap(unsigned a, unsigned b,
                                              unsigned& x, unsigned& y) {
#if __has_builtin(__builtin_amdgcn_permlane32_swap)
    auto rr = __builtin_amdgcn_permlane32_swap(a, b, false, false);
    x = rr[0]; y = rr[1];
#else
    int hi = (threadIdx.x & 63) >> 5;
    unsigned pb_ = __shfl_xor(b, 32), pa_ = __shfl_xor(a, 32);
    x = hi ? pb_ : a;
    y = hi ? b : pa_;
#endif
}

// Counted-vmcnt wait (T4): never drain to 0 in the steady-state loop.
#define VWAIT(N) do { asm volatile("s_waitcnt vmcnt(" #N ")" ::: "memory"); \
                      __builtin_amdgcn_sched_barrier(0); } while (0)
// Raw barrier WITHOUT the implicit vmcnt(0) drain of __syncthreads.
#define BAR() do { __builtin_amdgcn_s_barrier(); \
                   __builtin_amdgcn_sched_barrier(0); } while (0)
#define LGKM0_BAR() do { asm volatile("s_waitcnt lgkmcnt(0)" ::: "memory"); \
                         __builtin_amdgcn_sched_barrier(0); \
                         __builtin_amdgcn_s_barrier(); \
                         __builtin_amdgcn_sched_barrier(0); } while (0)

// blocks assigned to q-tile qt (proportional KV-split, chunk <= 7 tiles)
#define NBQ(qt) ((2 * (qt) + 8) / 7)
#define SWZ(r) ((((r) & 7) + ((r) >> 3)) & 7)

// ---------------------------------------------------------------------------
// Kernel 1: transpose W (f32 [512][64]) -> Wt (bf16 [3][64][512])
// ---------------------------------------------------------------------------
__global__ __launch_bounds__(256) void wtrans_kernel(
    const float* __restrict__ Wq, const float* __restrict__ Wk,
    const float* __restrict__ Wv, short* __restrict__ wt) {
    int tid = blockIdx.x * 256 + threadIdx.x;       // 0 .. 3*64*512-1
    int k = tid & (ND - 1);
    int c = (tid >> 9) & (NHD - 1);
    int m = tid >> 15;                              // 0..2
    const float* W = (m == 0) ? Wq : (m == 1) ? Wk : Wv;
    wt[tid] = f2bf(W[k * NHD + c]);                 // wt[(m*64+c)*512+k]
}

// ---------------------------------------------------------------------------
// Kernel 2: QKV projection GEMM (r17/r20 winner: 1-deep reg prefetch, raw
// barriers, SWZ swizzle, plain cached loads — r24's nt loads regressed).
// qkv x-stream is platform-bound ~2.6 TB/s for this pattern: issue depth
// (r18), registers (r16), barrier domains (r22), chunk size (r23), and
// cache policy (r24) were all null or worse.
// ---------------------------------------------------------------------------
__global__ __launch_bounds__(256, 4) void qkv_gemm_kernel(
    const float* __restrict__ x, const short* __restrict__ wt,
    short* __restrict__ qws, short* __restrict__ kws, short* __restrict__ vtws) {
    int t    = threadIdx.x;
    int lane = t & 63;
    int q16  = lane & 15;
    int g    = lane >> 4;
    int wv   = t >> 6;
    int wm   = wv >> 1, wn = wv & 1;
    long R0  = (long)blockIdx.x * 64;

    __shared__ __align__(16) short Xt[64 * 64];     // [token][k] 8KB swizzled
    __shared__ __align__(16) short Wl[192 * 64];    // [col][k]  24KB swizzled

    int xrow = t >> 4, xquad = t & 15;              // X: 4 rounds of 16 rows
    int wrow = t >> 3, wseg = t & 7;                // W: 6 rounds of 32 rows

    const float* xg = x + (R0 + xrow) * ND + xquad * 4;
    const short* wg = wt + wrow * ND + wseg * 8;

    f32x4 xr[4];
    bf16x8 wr[6];
    auto LOAD = [&](int ch) {
#pragma unroll
        for (int i = 0; i < 4; ++i)
            xr[i] = *(const f32x4*)(xg + (long)i * 16 * ND + ch * 64);
#pragma unroll
        for (int i = 0; i < 6; ++i)
            wr[i] = *(const bf16x8*)(wg + (long)i * 32 * ND + ch * 64);
    };
    auto STORE_LDS = [&]() {
#pragma unroll
        for (int i = 0; i < 4; ++i) {
            bf16x4 c;
#pragma unroll
            for (int j = 0; j < 4; ++j) c[j] = f2bf(xr[i][j]);
            int row = i * 16 + xrow;
            *(bf16x4*)((char*)Xt + row * 128 +
                       (((xquad >> 1) * 16) ^ (SWZ(row) << 4)) + (xquad & 1) * 8) = c;
        }
#pragma unroll
        for (int i = 0; i < 6; ++i) {
            int row = i * 32 + wrow;
            *(bf16x8*)((char*)Wl + row * 128 + ((wseg * 16) ^ (SWZ(row) << 4))) = wr[i];
        }
    };

    f32x4 acc[2][6];
#pragma unroll
    for (int mi = 0; mi < 2; ++mi)
#pragma unroll
        for (int ni = 0; ni < 6; ++ni) acc[mi][ni] = (f32x4){0.f, 0.f, 0.f, 0.f};

    LOAD(0);
    for (int ch = 0; ch < 8; ++ch) {
        STORE_LDS();                    // waits ONLY the regs it consumes
        if (ch + 1 < 8) LOAD(ch + 1);   // stays in flight across barriers
        LGKM0_BAR();                    // ds_writes visible; NO vmcnt drain
        __builtin_amdgcn_s_setprio(1);
#pragma unroll
        for (int kk = 0; kk < 2; ++kk) {
            bf16x8 a[2];
#pragma unroll
            for (int mi = 0; mi < 2; ++mi) {
                int row = wm * 32 + mi * 16 + q16;
                a[mi] = *(const bf16x8*)((char*)Xt + row * 128 +
                         ((kk * 64 + g * 16) ^ (SWZ(row) << 4)));
            }
#pragma unroll
            for (int ni = 0; ni < 6; ++ni) {
                int row = wn * 96 + ni * 16 + q16;
                bf16x8 b = *(const bf16x8*)((char*)Wl + row * 128 +
                            ((kk * 64 + g * 16) ^ (SWZ(row) << 4)));
                acc[0][ni] = __builtin_amdgcn_mfma_f32_16x16x32_bf16(a[0], b, acc[0][ni], 0, 0, 0);
                acc[1][ni] = __builtin_amdgcn_mfma_f32_16x16x32_bf16(a[1], b, acc[1][ni], 0, 0, 0);
            }
        }
        __builtin_amdgcn_s_setprio(0);
        BAR();                          // reads done; next STORE_LDS may write
    }

    int b = (int)(R0 >> 11);
#pragma unroll
    for (int mi = 0; mi < 2; ++mi) {
        long tok0 = R0 + wm * 32 + mi * 16 + g * 4;
#pragma unroll
        for (int ni = 0; ni < 6; ++ni) {
            int col = wn * 96 + ni * 16 + q16;
            int m = col >> 6, c64 = col & 63;       // uniform per (wn,ni)
            if (m == 0) {
#pragma unroll
                for (int r = 0; r < 4; ++r)
                    qws[(tok0 + r) * NHD + c64] = f2bf(acc[mi][ni][r] * QSCALE);
            } else if (m == 1) {
#pragma unroll
                for (int r = 0; r < 4; ++r)
                    kws[(tok0 + r) * NHD + c64] = f2bf(acc[mi][ni][r]);
            } else {
                bf16x4 vp;
#pragma unroll
                for (int r = 0; r < 4; ++r) vp[r] = f2bf(acc[mi][ni][r]);
                *(bf16x4*)(vtws + (long)(b * NHD + c64) * NT +
                           (int)(tok0 & 2047)) = vp;
            }
        }
    }
}

// ---------------------------------------------------------------------------
// Kernel 3: causal flash attention partial (r20, unchanged).
// ---------------------------------------------------------------------------
__global__ __launch_bounds__(256, 3) void attn_kernel(
    const short* __restrict__ qws, const short* __restrict__ kws,
    const short* __restrict__ vtws, short* __restrict__ Opart,
    float* __restrict__ lpart, float* __restrict__ out) {
    int bid  = blockIdx.x;
    int xcd  = bid & 7;
    int j    = bid >> 3;                // 0..91 within XCD
    int b    = xcd * 2 + (j >= 46);     // batch: 2 per XCD
    int j2   = (j >= 46) ? j - 46 : j;  // 0..45
    int qt = 0, chk = 0;
    {
        int acc = 0;
        for (int q = 15; q >= 0; --q) {
            int nbq = NBQ(q);
            if (j2 < acc + nbq) { qt = q; chk = j2 - acc; break; }
            acc += nbq;
        }
    }
    int n    = 2 * qt + 2;              // kv tiles covering this q-tile
    int nbq  = NBQ(qt);
    int tlo  = (chk * n) / nbq;
    int thi  = ((chk + 1) * n) / nbq;

    int tid  = threadIdx.x;
    int lane = tid & 63;
    int wv   = tid >> 6;                // 0..3
    int l31  = lane & 31;               // q column within wave tile
    int hi   = lane >> 5;

    __shared__ __align__(16) short Kt[3][64 * 64];  // [key][hd]  3x8KB swizzled
    __shared__ __align__(16) short Vt[3][64 * 64];  // [hd][key]  3x8KB swizzled

    int qr0w = qt * 128 + wv * 32;      // wave's first q row
    int qrow = qr0w + l31;

    const short* qb = qws + (long)(b * NT + qrow) * NHD;
    bf16x8 qf0 = *(const bf16x8*)(qb + hi * 8);
    bf16x8 qf1 = *(const bf16x8*)(qb + 16 + hi * 8);
    bf16x8 qf2 = *(const bf16x8*)(qb + 32 + hi * 8);
    bf16x8 qf3 = *(const bf16x8*)(qb + 48 + hi * 8);
    asm volatile("s_waitcnt vmcnt(0)" ::: "memory");
    asm volatile("" : "+v"(qf0), "+v"(qf1), "+v"(qf2), "+v"(qf3));
    __builtin_amdgcn_sched_barrier(0);

    int srow = tid >> 3, ssw = tid & 7;
    int sA_ = ssw ^ SWZ(srow);
    int sB_ = ssw ^ (((srow & 7) + (srow >> 3) + 4) & 7);      // rows +32
    const char* kT = (const char*)(kws  + (long)b * NT * NHD);
    const char* vT = (const char*)(vtws + (long)b * NHD * NT);
    auto STAGE = [&](int kv0, int buf) {            // 4 gll16 per thread
        char* lk = (char*)Kt + buf * 8192 + tid * 16;
        char* lv = (char*)Vt + buf * 8192 + tid * 16;
        gll16(kT + (long)(kv0 + srow) * 128 + sA_ * 16, lk);
        gll16(kT + (long)(kv0 + srow + 32) * 128 + sB_ * 16, lk + 4096);
        gll16(vT + (long)srow * 4096 + kv0 * 2 + sA_ * 16, lv);
        gll16(vT + (long)(srow + 32) * 4096 + kv0 * 2 + sB_ * 16, lv + 4096);
    };

    int swzq = SWZ(l31);
    int sw1  = swzq << 4;               // read-XOR for rows 0..31 (row = l31)
    int sw2  = ((swzq + 4) & 7) << 4;   // read-XOR for rows 32..63

    bf16x8 ones;
#pragma unroll
    for (int i = 0; i < 8; ++i) ones[i] = (short)0x3F80;   // bf16 1.0

    f32x16 oL, oH, lacc;
#pragma unroll
    for (int i = 0; i < 16; ++i) { oL[i] = 0.f; oH[i] = 0.f; lacc[i] = 0.f; }

    auto COMPUTE = [&](int kvi, int buf) {
        const char* kcur = (const char*)Kt + buf * 8192;
        const char* vcur = (const char*)Vt + buf * 8192;
        int k0 = kvi * 64;
        if (k0 > qr0w + 31) return;     // fully masked for this wave

        f32x16 sA, sB;
#pragma unroll
        for (int i = 0; i < 16; ++i) { sA[i] = 0.f; sB[i] = 0.f; }
        __builtin_amdgcn_s_setprio(1);
#pragma unroll
        for (int c = 0; c < 4; ++c) {
            bf16x8 qf = (c == 0) ? qf0 : (c == 1) ? qf1 : (c == 2) ? qf2 : qf3;
            bf16x8 kfA = *(const bf16x8*)(kcur + l31 * 128 +
                          ((c * 32 + hi * 16) ^ sw1));
            bf16x8 kfB = *(const bf16x8*)(kcur + (32 + l31) * 128 +
                          ((c * 32 + hi * 16) ^ sw2));
            sA = __builtin_amdgcn_mfma_f32_32x32x16_bf16(kfA, qf, sA, 0, 0, 0);
            sB = __builtin_amdgcn_mfma_f32_32x32x16_bf16(kfB, qf, sB, 0, 0, 0);
        }
        __builtin_amdgcn_s_setprio(0);

        bool msk = (k0 + 63 > qr0w);
        unsigned WA[8], WB[8];
#pragma unroll
        for (int m = 0; m < 4; ++m) {
#pragma unroll
            for (int t2 = 0; t2 < 4; ++t2) {
                int kloc = m * 8 + 4 * hi + t2;     // key within 32-block
                float va = sA[m * 4 + t2];
                float vb = sB[m * 4 + t2];
                if (msk) {
                    if (k0 + kloc > qrow)      va = -1e30f;
                    if (k0 + 32 + kloc > qrow) vb = -1e30f;
                }
                sA[m * 4 + t2] = fexp2(va);         // raw v_exp_f32
                sB[m * 4 + t2] = fexp2(vb);
            }
        }
#pragma unroll
        for (int p2 = 0; p2 < 8; ++p2) {            // raw v_cvt_pk_bf16_f32
            WA[p2] = cvtpk(sA[p2 * 2], sA[p2 * 2 + 1]);
            WB[p2] = cvtpk(sB[p2 * 2], sB[p2 * 2 + 1]);
        }

        bf16x8 pf0, pf1, pf2, pf3;
        {
            union { unsigned u[4]; bf16x8 v; } f;
            unsigned x, y;
            plswap(WA[0], WA[2], x, y); f.u[0] = x; f.u[2] = y;
            plswap(WA[1], WA[3], x, y); f.u[1] = x; f.u[3] = y;
            pf0 = f.v;
            plswap(WA[4], WA[6], x, y); f.u[0] = x; f.u[2] = y;
            plswap(WA[5], WA[7], x, y); f.u[1] = x; f.u[3] = y;
            pf1 = f.v;
            plswap(WB[0], WB[2], x, y); f.u[0] = x; f.u[2] = y;
            plswap(WB[1], WB[3], x, y); f.u[1] = x; f.u[3] = y;
            pf2 = f.v;
            plswap(WB[4], WB[6], x, y); f.u[0] = x; f.u[2] = y;
            plswap(WB[5], WB[7], x, y); f.u[1] = x; f.u[3] = y;
            pf3 = f.v;
        }

        __builtin_amdgcn_s_setprio(1);
#pragma unroll
        for (int kc = 0; kc < 4; ++kc) {
            bf16x8 pf = (kc == 0) ? pf0 : (kc == 1) ? pf1 : (kc == 2) ? pf2 : pf3;
            bf16x8 vfL = *(const bf16x8*)(vcur + l31 * 128 +
                          ((kc * 32 + hi * 16) ^ sw1));
            bf16x8 vfH = *(const bf16x8*)(vcur + (32 + l31) * 128 +
                          ((kc * 32 + hi * 16) ^ sw2));
            oL = __builtin_amdgcn_mfma_f32_32x32x16_bf16(vfL, pf, oL, 0, 0, 0);
            oH = __builtin_amdgcn_mfma_f32_32x32x16_bf16(vfH, pf, oH, 0, 0, 0);
            lacc = __builtin_amdgcn_mfma_f32_32x32x16_bf16(ones, pf, lacc, 0, 0, 0);
        }
        __builtin_amdgcn_s_setprio(0);
    };

    {
        int nt = thi - tlo;
        STAGE(tlo * 64, 0);
        if (nt > 1) STAGE((tlo + 1) * 64, 1);
        if (nt > 2) STAGE((tlo + 2) * 64, 2);

        int i = tlo, bc = 0;
        for (; i + 3 < thi; ++i) {
            VWAIT(8);
            BAR();
            COMPUTE(i, bc);
            BAR();
            STAGE((i + 3) * 64, bc);
            bc = (bc == 2) ? 0 : bc + 1;
        }
        if (thi - i == 3) {
            VWAIT(8); BAR(); COMPUTE(i, bc); BAR();
            bc = (bc == 2) ? 0 : bc + 1; ++i;
        }
        if (thi - i == 2) {
            VWAIT(4); BAR(); COMPUTE(i, bc); BAR();
            bc = (bc == 2) ? 0 : bc + 1; ++i;
        }
        if (thi - i == 1) {
            VWAIT(0); BAR(); COMPUTE(i, bc);
        }
    }

    if (nbq == 1) {
        // sole owner of these rows: normalized DIRECT output, no partials.
        float inv = 1.0f / lacc[0];
        float* od = out + ((long)(b << 11) + qt * 128 + wv * 32 + l31) * 64;
#pragma unroll
        for (int m = 0; m < 4; ++m) {
            f32x4 vL, vH;
#pragma unroll
            for (int t2 = 0; t2 < 4; ++t2) {
                vL[t2] = oL[m * 4 + t2] * inv;
                vH[t2] = oH[m * 4 + t2] * inv;
            }
            *(f32x4*)(od + m * 8 + 4 * hi)      = vL;
            *(f32x4*)(od + 32 + m * 8 + 4 * hi) = vH;
        }
        return;
    }

    // ---- epilogue: l = lacc[0] (all rows/cols of ones-MFMA equal) ----
    long prow = (long)chk * 32768 + (b << 11) + qt * 128 + wv * 32 + l31;
    short* od = Opart + prow * 64;
#pragma unroll
    for (int m = 0; m < 4; ++m) {
        bf16x4 a, c;
#pragma unroll
        for (int t2 = 0; t2 < 4; ++t2) { a[t2] = f2bf(oL[m * 4 + t2]); c[t2] = f2bf(oH[m * 4 + t2]); }
        *(bf16x4*)(od + m * 8 + 4 * hi)      = a;   // hd = m*8 + 4hi + t2
        *(bf16x4*)(od + 32 + m * 8 + 4 * hi) = c;   // hd block 32..63
    }
    if (hi == 0) lpart[prow] = lacc[0];
}

// ---------------------------------------------------------------------------
// Kernel 4: merge the per-(b,qt) chunk partials (qt>=3 only).
// ---------------------------------------------------------------------------
__global__ __launch_bounds__(256) void merge_kernel(
    const short* __restrict__ Opart, const float* __restrict__ lpart,
    float* __restrict__ out) {
    int idx  = blockIdx.x * 256 + threadIdx.x;      // 0 .. 262143
    int ridx = idx >> 3;                            // output row (== partial row)
    int h8   = idx & 7;                             // 8-hd chunk
    int qt   = (ridx >> 7) & 15;
    int nbq  = NBQ(qt);
    if (nbq == 1) return;                           // written directly by attn
    float lsum = 0.f;
    f32x4 r0 = (f32x4){0.f, 0.f, 0.f, 0.f};
    f32x4 r1 = (f32x4){0.f, 0.f, 0.f, 0.f};
    for (int s = 0; s < nbq; ++s) {
        lsum += lpart[s * 32768 + ridx];
        bf16x8 a = *(const bf16x8*)(Opart + (long)s * 2097152 + (long)ridx * 64 + h8 * 8);
#pragma unroll
        for (int jj = 0; jj < 4; ++jj) {
            r0[jj] += bf2f(a[jj]);
            r1[jj] += bf2f(a[4 + jj]);
        }
    }
    float inv = 1.0f / lsum;
    r0 *= inv; r1 *= inv;
    float* dst = out + (long)ridx * 64 + h8 * 8;
    *(f32x4*)dst = r0;
    *(f32x4*)(dst + 4) = r1;
}

// ---------------------------------------------------------------------------
extern "C" void kernel_launch(void* const* d_in, const int* in_sizes, int n_in,
                              void* d_out, int out_size, void* d_ws, size_t ws_size,
                              hipStream_t stream) {
    const float* x  = (const float*)d_in[0];
    const float* Wq = (const float*)d_in[1];
    const float* Wk = (const float*)d_in[2];
    const float* Wv = (const float*)d_in[3];
    float* out = (float*)d_out;

    float* fb    = (float*)d_ws;
    float* lpart = fb;                              // 5*32768 f32 (640KB)
    short* Opart = (short*)(fb + 5 * 32768);        // 5*32768*64 bf16 (20MB)
    short* qws   = Opart + (long)5 * 2097152;       // [32768][64] bf16 (pre-scaled)
    short* kws   = qws + (long)2097152;             // [32768][64] bf16
    short* vtws  = kws + (long)2097152;             // [16][64][2048] bf16
    short* wt    = vtws + (long)2097152;            // [3][64][512] bf16

    wtrans_kernel<<<384, 256, 0, stream>>>(Wq, Wk, Wv, wt);
    qkv_gemm_kernel<<<512, 256, 0, stream>>>(x, wt, qws, kws, vtws);
    attn_kernel<<<736, 256, 0, stream>>>(qws, kws, vtws, Opart, lpart, out);
    merge_kernel<<<1024, 256, 0, stream>>>(Opart, lpart, out);
}